// Round 19
// baseline (187.429 us; speedup 1.0000x reference)
//
#include <hip/hip_runtime.h>
#include <hip/hip_cooperative_groups.h>

namespace cg = cooperative_groups;

// Chamfer loss: B=4, N=M=8192, D=3, fp32 in, scalar fp32 out.
// loss = mean_n min_m ||x_n-y_m||^2 + mean_m min_n ||...||^2 + lambda*bpp
//
// R18 = R15 (best verified: 40.6us, pass ~31us) fused into ONE
// cooperative kernel. Measured overhead outside the pass was ~8.7us
// (prep + 2 reduce kernels + 4 launches; R8: 94-85, R13: 73.6-65).
// 512 blocks x 256 threads (2 blocks/CU -> co-residency guaranteed),
// each block runs 2 pass units sequentially (R11 proved waves/SIMD is
// null for the pass). Phases: prep | sync | pass | sync | row-combine +
// block partials | sync | block-0 finale. Fixed-tree sums: deterministic.
// Pass math (R15-verified, absmax 0.0): P = n2 - 2 a.y, one k-octet:
//   k0-5: -2a_d*(yhi_d|ylo_d)  k6: 1*n2hi  k7: 1*n2lo
// a = bf16(x) query (reduce adds ||a||^2 consistently); A lanes 32-63
// zero octet; B loads duplicate across lane halves (k8-15 dead).
// A frag row=lane&31; C/D col=lane&31, row=(q&3)+8*(q>>2)+4*(lane>>5).

typedef float  f16v __attribute__((ext_vector_type(16)));
typedef short  s8   __attribute__((ext_vector_type(8)));

#define NPTS   8192
#define NB     4
#define NPTOT  (NB * NPTS)        // 32768 points per cloud
#define GRID_B 512

__device__ __forceinline__ ushort f2bf(float f) {
    uint u = __float_as_uint(f);
    u += 0x7FFF + ((u >> 16) & 1);          // round-to-nearest-even
    return (ushort)(u >> 16);
}
__device__ __forceinline__ float bf2f(ushort h) {
    return __uint_as_float(((uint)h) << 16);
}
__device__ __forceinline__ uint pk(ushort lo, ushort hi) {
    return (uint)lo | ((uint)hi << 16);
}

#define LOADG(G, g)                                                        \
    _Pragma("unroll")                                                      \
    for (int u = 0; u < 4; u++)                                            \
        G[u] = *(const s8*)(Bseg + (size_t)((g) * 4 + u) * 32 + bcol);

#define COMPG(G)                                                           \
    _Pragma("unroll")                                                      \
    for (int u = 0; u < 4; u += 2) {                                       \
        f16v acc0 = __builtin_amdgcn_mfma_f32_32x32x16_bf16(               \
            afrag, G[u], zero16, 0, 0, 0);                                 \
        f16v acc1 = __builtin_amdgcn_mfma_f32_32x32x16_bf16(               \
            afrag, G[u + 1], zero16, 0, 0, 0);                             \
        _Pragma("unroll")                                                  \
        for (int q = 0; q < 16; q++)                                       \
            racc[q] = fminf(fminf(acc0[q], acc1[q]), racc[q]);             \
    }

__global__ __launch_bounds__(256) void fused(
        const float* __restrict__ X, const float* __restrict__ Y,
        const float* __restrict__ bpp, const float* __restrict__ lam,
        uint4* __restrict__ Arec, uint4* __restrict__ Brec,
        float* __restrict__ minsP, float* __restrict__ partials,
        float* __restrict__ out) {
    cg::grid_group grid = cg::this_grid();
    int tid = threadIdx.x;
    int bidx = blockIdx.x;
    int gid = bidx * 256 + tid;             // 0 .. 131071

    // ---------------- phase 1: prep (65536 records) ----------------
    if (gid < 2 * NPTOT) {
        int i = gid;
        const float* src = (i < NPTOT) ? X : Y;
        int p = i & (NPTOT - 1);
        float x0 = src[3*p], x1 = src[3*p+1], x2 = src[3*p+2];

        ushort a0 = f2bf(x0), a1 = f2bf(x1), a2 = f2bf(x2);
        float f0 = bf2f(a0), f1 = bf2f(a1), f2v = bf2f(a2);
        ushort m0 = f2bf(-2.0f * f0), m1 = f2bf(-2.0f * f1);
        ushort m2 = f2bf(-2.0f * f2v);
        const ushort ONE = 0x3F80;
        Arec[i] = make_uint4(pk(m0, m1), pk(m2, m0), pk(m1, m2), pk(ONE, ONE));

        ushort l0 = f2bf(x0 - f0), l1 = f2bf(x1 - f1), l2 = f2bf(x2 - f2v);
        float n2 = __fmaf_rn(x0, x0, __fmaf_rn(x1, x1, x2 * x2));
        ushort nh = f2bf(n2);
        ushort nl = f2bf(n2 - bf2f(nh));
        Brec[i] = make_uint4(pk(a0, a1), pk(a2, l0), pk(l1, l2), pk(nh, nl));
    }
    grid.sync();

    // ---------------- phase 2: mfma pass (2 units/block) ----------------
    int lane = tid & 63;
    int wave = tid >> 6;
    const s8 zf = {0, 0, 0, 0, 0, 0, 0, 0};
    const f16v zero16 = {0,0,0,0,0,0,0,0,0,0,0,0,0,0,0,0};

    for (int uu = 0; uu < 2; uu++) {
        int unit = bidx + uu * GRID_B;      // 0..1023
        int pass = unit >> 9;               // 0: rows=X; 1: rows=Y
        int r    = unit & 511;
        int b    = r >> 7;
        int rem  = r & 127;
        int blk  = rem >> 1;
        int seg  = rem & 1;
        int ca   = pass;
        int cb   = 1 - pass;
        int ibase = (blk * 4 + wave) * 32;

        int pA = b * NPTS + ibase + (lane & 31);
        s8 afrag = (lane < 32)
            ? *(const s8*)&Arec[(size_t)ca * NPTOT + pA] : zf;

        const uint4* Bseg = Brec + (size_t)cb * NPTOT + (size_t)b * NPTS
                          + (size_t)seg * 4096;
        int bcol = lane & 31;

        f16v racc;
#pragma unroll
        for (int q = 0; q < 16; q++) racc[q] = 3.0e38f;

        s8 GA[4], GB[4];
        LOADG(GA, 0);
        for (int g = 0; g < 30; g += 2) {
            LOADG(GB, g + 1);
            COMPG(GA);
            LOADG(GA, g + 2);
            COMPG(GB);
        }
        LOADG(GB, 31);
        COMPG(GA);
        COMPG(GB);

        // row-min across the 32 cols (lane bits 0-4)
#pragma unroll
        for (int q = 0; q < 16; q++) {
            float v = racc[q];
            v = fminf(v, __shfl_xor(v, 1, 64));
            v = fminf(v, __shfl_xor(v, 2, 64));
            v = fminf(v, __shfl_xor(v, 4, 64));
            v = fminf(v, __shfl_xor(v, 8, 64));
            v = fminf(v, __shfl_xor(v, 16, 64));
            racc[q] = v;
        }
        if ((lane & 31) == 0) {
            float* dst = minsP + ((size_t)seg * 2 + pass) * NPTOT
                       + (size_t)b * NPTS + ibase;
            int half = lane >> 5;
#pragma unroll
            for (int q = 0; q < 16; q++)
                dst[(q & 3) + 8 * (q >> 2) + 4 * half] = racc[q];
        }
    }
    grid.sync();

    // ------- phase 3: per-row combine (+||a||^2) + block partial -------
    __shared__ float sred[256];
    float val = 0.0f;
    if (gid < 2 * NPTOT) {
        int pass = gid >> 15;
        int rI   = gid & (NPTOT - 1);
        float mn = fminf(minsP[(size_t)(0 + pass) * NPTOT + rI],
                         minsP[(size_t)(2 + pass) * NPTOT + rI]);
        const float* src = pass ? Y : X;
        float a  = bf2f(f2bf(src[3*rI]));
        float b2 = bf2f(f2bf(src[3*rI+1]));
        float c  = bf2f(f2bf(src[3*rI+2]));
        val = mn + __fmaf_rn(a, a, __fmaf_rn(b2, b2, c * c));
    }
    sred[tid] = val;
    __syncthreads();
    for (int s = 128; s > 0; s >>= 1) {
        if (tid < s) sred[tid] += sred[tid + s];
        __syncthreads();
    }
    if (tid == 0) partials[bidx] = sred[0];
    grid.sync();

    // ---------------- phase 4: block 0 finale ----------------
    if (bidx == 0) {
        float v = partials[tid] + partials[tid + 256];
        __syncthreads();          // reuse sred safely
        sred[tid] = v;
        __syncthreads();
        for (int s = 128; s > 0; s >>= 1) {
            if (tid < s) sred[tid] += sred[tid + s];
            __syncthreads();
        }
        if (tid == 0)
            out[0] = sred[0] * (1.0f / (float)NPTOT) + lam[0] * bpp[0];
    }
}

extern "C" void kernel_launch(void* const* d_in, const int* in_sizes, int n_in,
                              void* d_out, int out_size, void* d_ws, size_t ws_size,
                              hipStream_t stream) {
    const float* X   = (const float*)d_in[0];   // pc_pred  [4,8192,3]
    const float* Y   = (const float*)d_in[1];   // pc_target[4,8192,3]
    const float* bpp = (const float*)d_in[2];
    const float* lam = (const float*)d_in[3];
    float* out = (float*)d_out;

    char* w = (char*)d_ws;
    float*  partials = (float*)w;               w += GRID_B * sizeof(float);
    float*  minsP    = (float*)w;               w += (size_t)4 * NPTOT * sizeof(float);
    uint4*  Arec     = (uint4*)w;               w += (size_t)2 * NPTOT * sizeof(uint4);
    uint4*  Brec     = (uint4*)w;

    void* args[] = {(void*)&X, (void*)&Y, (void*)&bpp, (void*)&lam,
                    (void*)&Arec, (void*)&Brec, (void*)&minsP,
                    (void*)&partials, (void*)&out};
    hipLaunchCooperativeKernel((const void*)fused, dim3(GRID_B), dim3(256),
                               args, 0, stream);
}

// Round 20
// 40.528 us; speedup vs baseline: 4.6247x; 4.6247x over previous
//
#include <hip/hip_runtime.h>

// Chamfer loss: B=4, N=M=8192, D=3, fp32 in, scalar fp32 out.
// loss = mean_n min_m ||x_n-y_m||^2 + mean_m min_n ||...||^2 + lambda*bpp
//
// R19 = R15 verbatim (best verified: 40.57us). Reverted after R18's
// cooperative fusion regressed 4.6x (compiler capped VGPR at 60 for the
// multi-phase kernel -> pass working set spilled to scratch).
// Experiment ledger on the ~31us pass (all null or negative):
//   R11 occupancy x2 | R12 merge-VALU /2 | R13/R7/R9 2-A-frags (AGPR tax)
//   R8 16x16x32 shape | R10 inline-asm MFMA | R15 unique-bytes /2 (kept:
//   absmax 0.0, smaller records) | R16 VMEM instrs /8 via LDS staging |
//   R17 MFMA count /2 + col-min fusion | R18 single-kernel fusion.
// Structure: P = n2 - 2 a.y computed by one 32x32x16 bf16 MFMA per
// 32x32 tile, K=8 of 16:
//   k0-5: -2a_d*(yhi_d|ylo_d)   k6: 1*n2hi   k7: 1*n2lo
// a = bf16(x) query (error enters mean with random sign, ~1e-4 final;
// reduce1 adds ||a||^2 consistently). A-frag: lanes 0-31 real octet
// (row=lane&31), lanes 32-63 ZERO (k8-15 dead); B: 16B record per point,
// all lanes read record lane&31. C/D: col=lane&31,
// row=(q&3)+8*(q>>2)+4*(lane>>5). Grid 1024 (pass2 x b4 x rowblk64 x
// seg2), 4 waves/block, wave = 32 rows x 4096-pt segment, 4-tile
// ping-pong prefetch groups, paired v_min3 merge (<=2 acc tiles live).

typedef float  f16v __attribute__((ext_vector_type(16)));
typedef short  s8   __attribute__((ext_vector_type(8)));

#define NPTS   8192
#define NB     4
#define NPTOT  (NB * NPTS)        // 32768 points per cloud
#define NSEG   2                  // column-segment split (4096 cols each)
#define RBLK   128

__device__ __forceinline__ ushort f2bf(float f) {
    uint u = __float_as_uint(f);
    u += 0x7FFF + ((u >> 16) & 1);          // round-to-nearest-even
    return (ushort)(u >> 16);
}
__device__ __forceinline__ float bf2f(ushort h) {
    return __uint_as_float(((uint)h) << 16);
}
__device__ __forceinline__ uint pk(ushort lo, ushort hi) {
    return (uint)lo | ((uint)hi << 16);
}

// prep: per point i (both clouds): one 16B A-record and one 16B B-record.
__global__ __launch_bounds__(256) void prep(
        const float* __restrict__ X, const float* __restrict__ Y,
        uint4* __restrict__ Arec, uint4* __restrict__ Brec) {
    int i = blockIdx.x * 256 + threadIdx.x;
    if (i >= 2 * NPTOT) return;
    const float* src = (i < NPTOT) ? X : Y;
    int p = i & (NPTOT - 1);
    float x0 = src[3*p], x1 = src[3*p+1], x2 = src[3*p+2];

    // A-side: a = bf16(x), -2a exact in bf16
    ushort a0 = f2bf(x0), a1 = f2bf(x1), a2 = f2bf(x2);
    float f0 = bf2f(a0), f1 = bf2f(a1), f2v = bf2f(a2);
    ushort m0 = f2bf(-2.0f * f0), m1 = f2bf(-2.0f * f1), m2 = f2bf(-2.0f * f2v);
    const ushort ONE = 0x3F80;
    Arec[i] = make_uint4(pk(m0, m1), pk(m2, m0), pk(m1, m2), pk(ONE, ONE));

    // B-side: y exact via hi/lo; n2 = ||y||^2 via hi/lo
    ushort l0 = f2bf(x0 - f0), l1 = f2bf(x1 - f1), l2 = f2bf(x2 - f2v);
    float n2 = __fmaf_rn(x0, x0, __fmaf_rn(x1, x1, x2 * x2));
    ushort nh = f2bf(n2);
    ushort nl = f2bf(n2 - bf2f(nh));
    Brec[i] = make_uint4(pk(a0, a1), pk(a2, l0), pk(l1, l2), pk(nh, nl));
}

#define LOADG(G, g)                                                        \
    _Pragma("unroll")                                                      \
    for (int u = 0; u < 4; u++)                                            \
        G[u] = *(const s8*)(Bseg + (size_t)((g) * 4 + u) * 32 + bcol);

// paired merge: 2 MFMAs then 16 min3 (2 acc tiles live, 32 regs max)
#define COMPG(G)                                                           \
    _Pragma("unroll")                                                      \
    for (int u = 0; u < 4; u += 2) {                                       \
        f16v acc0 = __builtin_amdgcn_mfma_f32_32x32x16_bf16(               \
            afrag, G[u], zero16, 0, 0, 0);                                 \
        f16v acc1 = __builtin_amdgcn_mfma_f32_32x32x16_bf16(               \
            afrag, G[u + 1], zero16, 0, 0, 0);                             \
        _Pragma("unroll")                                                  \
        for (int q = 0; q < 16; q++)                                       \
            racc[q] = fminf(fminf(acc0[q], acc1[q]), racc[q]);             \
    }

__global__ __launch_bounds__(256) void mfma_pass(
        const uint4* __restrict__ Arec, const uint4* __restrict__ Brec,
        float* __restrict__ minsP) {
    // grid = 1024: pass(2) x batch(4) x rowblk(64) x seg(2)
    // block = 4 waves; wave owns 32 rows x one 4096-col segment
    int bid  = blockIdx.x;
    int pass = bid >> 9;            // 0: rows=X cols=Y; 1: rows=Y cols=X
    int r    = bid & 511;
    int b    = r >> 7;
    int rem  = r & 127;
    int blk  = rem >> 1;
    int seg  = rem & 1;
    int lane = threadIdx.x & 63;
    int wave = threadIdx.x >> 6;
    int ca   = pass;                // A-cloud: 0=X,1=Y
    int cb   = 1 - pass;
    int ibase = (blk * 4 + wave) * 32;

    const s8 zf = {0, 0, 0, 0, 0, 0, 0, 0};

    // A fragment: lanes 0-31 real (row = lane&31), lanes 32-63 zero octet
    int pA = b * NPTS + ibase + (lane & 31);
    s8 afrag = (lane < 32)
        ? *(const s8*)&Arec[(size_t)ca * NPTOT + pA] : zf;

    // B segment: 4096 points = 128 col-tiles of 32 records (16B each)
    const uint4* Bseg = Brec + (size_t)cb * NPTOT + (size_t)b * NPTS
                      + (size_t)seg * 4096;
    int bcol = lane & 31;           // lanes 32-63 duplicate (A side is 0)

    const f16v zero16 = {0,0,0,0,0,0,0,0,0,0,0,0,0,0,0,0};
    f16v racc;
#pragma unroll
    for (int q = 0; q < 16; q++) racc[q] = 3.0e38f;

    // 32 groups of 4 col-tiles, ping-pong prefetch
    s8 GA[4], GB[4];
    LOADG(GA, 0);
    for (int g = 0; g < 30; g += 2) {
        LOADG(GB, g + 1);
        COMPG(GA);
        LOADG(GA, g + 2);
        COMPG(GB);
    }
    LOADG(GB, 31);
    COMPG(GA);
    COMPG(GB);

    // row-min across the 32 cols (lane bits 0-4), rows stay fixed
#pragma unroll
    for (int q = 0; q < 16; q++) {
        float v = racc[q];
        v = fminf(v, __shfl_xor(v, 1, 64));
        v = fminf(v, __shfl_xor(v, 2, 64));
        v = fminf(v, __shfl_xor(v, 4, 64));
        v = fminf(v, __shfl_xor(v, 8, 64));
        v = fminf(v, __shfl_xor(v, 16, 64));
        racc[q] = v;
    }
    if ((lane & 31) == 0) {
        float* dst = minsP + ((size_t)seg * 2 + pass) * NPTOT
                   + (size_t)b * NPTS + ibase;
        int half = lane >> 5;       // row offset +4 for lanes 32..63
#pragma unroll
        for (int q = 0; q < 16; q++)
            dst[(q & 3) + 8 * (q >> 2) + 4 * half] = racc[q];
    }
}

__global__ __launch_bounds__(256) void reduce1(
        const float* __restrict__ minsP,
        const float* __restrict__ X, const float* __restrict__ Y,
        float2* __restrict__ out2) {
    __shared__ float s1[256], s2[256];
    int t = threadIdx.x;
    int i = blockIdx.x * 256 + t;           // RBLK*256 == NPTOT exactly
    float mx = 3.0e38f, my = 3.0e38f;
#pragma unroll
    for (int s = 0; s < NSEG; s++) {
        mx = fminf(mx, minsP[((size_t)s * 2 + 0) * NPTOT + i]);
        my = fminf(my, minsP[((size_t)s * 2 + 1) * NPTOT + i]);
    }
    // add ||a||^2 with a = bf16-rounded query coords (consistent with MFMA)
    float a = bf2f(f2bf(X[3*i]));
    float bb = bf2f(f2bf(X[3*i+1]));
    float c = bf2f(f2bf(X[3*i+2]));
    float sx = mx + __fmaf_rn(a, a, __fmaf_rn(bb, bb, c * c));
    float d = bf2f(f2bf(Y[3*i]));
    float e = bf2f(f2bf(Y[3*i+1]));
    float f = bf2f(f2bf(Y[3*i+2]));
    float sy = my + __fmaf_rn(d, d, __fmaf_rn(e, e, f * f));
    s1[t] = sx; s2[t] = sy;
    __syncthreads();
    for (int s = 128; s > 0; s >>= 1) {
        if (t < s) { s1[t] += s1[t + s]; s2[t] += s2[t + s]; }
        __syncthreads();
    }
    if (t == 0) out2[blockIdx.x] = make_float2(s1[0], s2[0]);
}

__global__ __launch_bounds__(RBLK) void reduce2(
        const float2* __restrict__ p2,
        const float* __restrict__ bpp, const float* __restrict__ lam,
        float* __restrict__ out) {
    __shared__ float s[RBLK];
    int t = threadIdx.x;
    float2 p = p2[t];
    s[t] = p.x + p.y;
    __syncthreads();
    for (int h = RBLK / 2; h > 0; h >>= 1) {
        if (t < h) s[t] += s[t + h];
        __syncthreads();
    }
    if (t == 0) out[0] = s[0] * (1.0f / (float)NPTOT) + lam[0] * bpp[0];
}

extern "C" void kernel_launch(void* const* d_in, const int* in_sizes, int n_in,
                              void* d_out, int out_size, void* d_ws, size_t ws_size,
                              hipStream_t stream) {
    const float* X   = (const float*)d_in[0];   // pc_pred  [4,8192,3]
    const float* Y   = (const float*)d_in[1];   // pc_target[4,8192,3]
    const float* bpp = (const float*)d_in[2];
    const float* lam = (const float*)d_in[3];
    float* out = (float*)d_out;

    char* w = (char*)d_ws;
    float2* p2    = (float2*)w;                 w += 1024;
    float*  minsP = (float*)w;                  w += (size_t)NSEG * 2 * NPTOT * sizeof(float);
    uint4*  Arec  = (uint4*)w;                  w += (size_t)2 * NPTOT * sizeof(uint4);
    uint4*  Brec  = (uint4*)w;

    prep<<<(2 * NPTOT + 255) / 256, 256, 0, stream>>>(X, Y, Arec, Brec);
    mfma_pass<<<1024, 256, 0, stream>>>(Arec, Brec, minsP);
    reduce1<<<RBLK, 256, 0, stream>>>(minsP, X, Y, p2);
    reduce2<<<1, RBLK, 0, stream>>>(p2, bpp, lam, out);
}